// Round 9
// baseline (33.113 us; speedup 1.0000x reference)
//
#include <hip/hip_runtime.h>
#include <hip/hip_bf16.h>
#include <math.h>

#define D    128
#define NT   256             // B*T
#define HD   32
#define LD   32
#define PADW 132             // padded row length (f32 / u16 elems)

static __device__ inline unsigned short f2bf(float f) {
    __hip_bfloat16 b = __float2bfloat16(f);
    return *reinterpret_cast<unsigned short*>(&b);
}
static __device__ inline float bf2f(unsigned int u16v) {
    union { unsigned int i; float f; } v;
    v.i = u16v << 16;
    return v.f;
}

union SmemA {                        // z (P1) overlaid with lin (P2+)
    float zt[LD][PADW];              // z transposed zt[l][i], 16.9 KB
    float lin[2][D];                 // full rank-1 terms, 1 KB
};
union SmemB {                        // pa/pb (P1-P3) overlaid with S-transpose buf
    struct { float spa[HD][PADW]; float spb[HD][PADW]; } p;   // 33.8 KB
    unsigned short st[D][PADW];                               // 33.8 KB
};

// ---------------------------------------------------------------------------
// K12: one block per token n, 1024 threads (16 waves/CU = 4/SIMD; 2x R8 occ).
//  P1: thread (h, i-quad): pa'[h][i], pb[h][i] -> LDS h-major. W1 in VGPRs.
//  P2: 256 threads: full 32-h column sums -> lin[kind][i] (relu-split rank-1).
//  P3: thread (ty,tx) = 4i x 4j: per h: 2 lane-ish-distinct b128 + 32 VALU.
//  epi: S -> bf16 LDS transpose -> write ONLY D = S - S^T (8 MB total).
// ---------------------------------------------------------------------------
__global__ __launch_bounds__(1024, 4) void fused_pab_scores(
    const float* __restrict__ z, const float* __restrict__ W1,
    const float* __restrict__ b1, const float* __restrict__ W2,
    unsigned short* __restrict__ Dp)
{
    __shared__ SmemA sa;
    __shared__ SmemB sb;

    const int t = threadIdx.x;
    const int n = blockIdx.x;

    // ---- stage z transposed: 1024 float4, 1/thread ----
    {
        const float4* zsrc = (const float4*)(z + (size_t)n * (D * LD));
        float4 v = zsrc[t];
        int i = t >> 3;                  // 0..127
        int l = (t & 7) * 4;             // 0..28
        sa.zt[l + 0][i] = v.x; sa.zt[l + 1][i] = v.y;
        sa.zt[l + 2][i] = v.z; sa.zt[l + 3][i] = v.w;
    }

    // ---- W1 row h into VGPRs ----
    const int h  = t & 31;
    const int iq = t >> 5;               // 0..31
    float wa[LD], wb[LD];
    #pragma unroll
    for (int k = 0; k < 8; ++k) {
        *(float4*)&wa[k*4] = *(const float4*)&W1[h * 64 + k*4];
        *(float4*)&wb[k*4] = *(const float4*)&W1[h * 64 + 32 + k*4];
    }
    const float bias = b1[h];
    __syncthreads();

    // ---- P1: 4 i's x 1 h, 8 independent fma chains ----
    {
        float a[4], c[4];
        #pragma unroll
        for (int r = 0; r < 4; ++r) { a[r] = bias; c[r] = 0.f; }
        #pragma unroll
        for (int l = 0; l < LD; ++l) {
            float4 zv = *(const float4*)&sa.zt[l][iq * 4];
            float zr[4] = {zv.x, zv.y, zv.z, zv.w};
            #pragma unroll
            for (int r = 0; r < 4; ++r) {
                a[r] = fmaf(zr[r], wa[l], a[r]);
                c[r] = fmaf(zr[r], wb[l], c[r]);
            }
        }
        *(float4*)&sb.p.spa[h][iq * 4] = make_float4(a[0], a[1], a[2], a[3]);
        *(float4*)&sb.p.spb[h][iq * 4] = make_float4(c[0], c[1], c[2], c[3]);
    }
    __syncthreads();                     // zt dead after here

    float w2r[HD];                       // uniform -> scalarized
    #pragma unroll
    for (int q = 0; q < HD; ++q) w2r[q] = 0.5f * W2[q];

    // ---- P2: rank-1 linear terms (relu(x) = x/2 + |x|/2), 256 threads ----
    if (t < 256) {
        const int kind = t >> 7, i2 = t & 127;
        float s = 0.f;
        #pragma unroll
        for (int hq = 0; hq < HD; ++hq) {
            float v = kind ? sb.p.spb[hq][i2] : sb.p.spa[hq][i2];
            s = fmaf(w2r[hq], v, s);
        }
        sa.lin[kind][i2] = s;
    }
    __syncthreads();

    // ---- P3: abs part, 4i x 4j per thread ----
    const int tx = t & 31;               // j-quad
    const int ty = t >> 5;               // i-quad
    float acc[4][4];
    #pragma unroll
    for (int r = 0; r < 4; ++r)
        #pragma unroll
        for (int c = 0; c < 4; ++c) acc[r][c] = 0.f;

    #pragma unroll 4
    for (int hh = 0; hh < HD; ++hh) {
        float4 av = *(const float4*)&sb.p.spa[hh][ty * 4];
        float4 bv = *(const float4*)&sb.p.spb[hh][tx * 4];
        const float w = w2r[hh];
        float ar[4] = {av.x, av.y, av.z, av.w};
        float br[4] = {bv.x, bv.y, bv.z, bv.w};
        #pragma unroll
        for (int r = 0; r < 4; ++r)
            #pragma unroll
            for (int c = 0; c < 4; ++c)
                acc[r][c] = fmaf(w, fabsf(ar[r] + br[c]), acc[r][c]);
    }

    // ---- add linear terms ----
    {
        float cai[4], cbj[4];
        #pragma unroll
        for (int r = 0; r < 4; ++r) cai[r] = sa.lin[0][ty * 4 + r];
        #pragma unroll
        for (int c = 0; c < 4; ++c) cbj[c] = sa.lin[1][tx * 4 + c];
        #pragma unroll
        for (int r = 0; r < 4; ++r)
            #pragma unroll
            for (int c = 0; c < 4; ++c)
                acc[r][c] += cai[r] + cbj[c];
    }
    __syncthreads();                     // spa/spb dead -> st overlay

    // ---- epilogue: S -> bf16 LDS, in-block transpose, write D only ----
    #pragma unroll
    for (int r = 0; r < 4; ++r) {
        unsigned int p0 = ((unsigned int)f2bf(acc[r][1]) << 16) | f2bf(acc[r][0]);
        unsigned int p1 = ((unsigned int)f2bf(acc[r][3]) << 16) | f2bf(acc[r][2]);
        *(uint2*)&sb.st[ty * 4 + r][tx * 4] = make_uint2(p0, p1);
    }
    __syncthreads();

    unsigned short* Dn = Dp + (size_t)n * (D * D);
    float dre[4][4];
    #pragma unroll
    for (int c = 0; c < 4; ++c) {
        int j = tx * 4 + c;
        uint2 tv = *(const uint2*)&sb.st[j][ty * 4];    // S[j][ty*4..+3]
        dre[0][c] = acc[0][c] - bf2f(tv.x & 0xffff);
        dre[1][c] = acc[1][c] - bf2f(tv.x >> 16);
        dre[2][c] = acc[2][c] - bf2f(tv.y & 0xffff);
        dre[3][c] = acc[3][c] - bf2f(tv.y >> 16);
    }
    #pragma unroll
    for (int r = 0; r < 4; ++r) {
        unsigned int p0 = ((unsigned int)f2bf(dre[r][1]) << 16) | f2bf(dre[r][0]);
        unsigned int p1 = ((unsigned int)f2bf(dre[r][3]) << 16) | f2bf(dre[r][2]);
        *(uint2*)&Dn[(ty * 4 + r) * D + tx * 4] = make_uint2(p0, p1);
    }
}

// ---------------------------------------------------------------------------
// K3: mean over n of D (8 MB, coalesced uint2), sigmoid/Wm finalize.
// grid 256: block = (row, j-half). thread (g = 16 n-groups, jq = 16 j-quads).
// ---------------------------------------------------------------------------
__global__ __launch_bounds__(256) void finalize_kernel(
    const unsigned short* __restrict__ Dp, const float* __restrict__ Wmag,
    float* __restrict__ out)
{
    __shared__ float red[16][68];

    const int t    = threadIdx.x;
    const int row  = blockIdx.x >> 1;
    const int half = blockIdx.x & 1;
    const int g    = t >> 4;             // n-group 0..15 (16 n's each)
    const int jq   = t & 15;             // j-quad within half
    const int jloc = jq * 4;

    float a4[4] = {0.f, 0.f, 0.f, 0.f};
    #pragma unroll 4
    for (int q = 0; q < 16; ++q) {
        int nn = g * 16 + q;
        uint2 u = *(const uint2*)&Dp[(size_t)nn * (D * D) + row * D + half * 64 + jloc];
        a4[0] += bf2f(u.x & 0xffff); a4[1] += bf2f(u.x >> 16);
        a4[2] += bf2f(u.y & 0xffff); a4[3] += bf2f(u.y >> 16);
    }
    *(float4*)&red[g][jloc] = make_float4(a4[0], a4[1], a4[2], a4[3]);
    __syncthreads();

    if (t < 64) {
        const int j = half * 64 + t;
        float s = 0.f;
        #pragma unroll
        for (int gg = 0; gg < 16; ++gg) s += red[gg][t];

        const int idx = row * D + j;
        float av  = s * (1.0f / 256.0f);     // mean over n; TAU = 1
        float dir = 1.0f / (1.0f + __expf(-av));
        float wm  = 0.5f * (Wmag[row * D + j] + Wmag[j * D + row]);
        float A;
        if (row == j) { wm = 0.f; A = 0.f; }
        else          { A = dir / (1.0f + __expf(-wm)); }
        out[idx]         = A;
        out[D * D + idx] = wm;
    }
}

extern "C" void kernel_launch(void* const* d_in, const int* in_sizes, int n_in,
                              void* d_out, int out_size, void* d_ws, size_t ws_size,
                              hipStream_t stream)
{
    const float* z    = (const float*)d_in[0];   // (4,64,128,32)
    const float* Wmag = (const float*)d_in[1];   // (128,128)
    const float* W1   = (const float*)d_in[2];   // (32,64)
    const float* b1   = (const float*)d_in[3];   // (32,)
    const float* W2   = (const float*)d_in[4];   // (1,32)
    // d_in[5] = b2: cancels in scores - scores^T.

    unsigned short* Dp = (unsigned short*)d_ws;  // bf16 D[n][i][j], 8 MB
    float* out = (float*)d_out;

    fused_pab_scores<<<NT, 1024, 0, stream>>>(z, W1, b1, W2, Dp);
    finalize_kernel<<<NT, 256, 0, stream>>>(Dp, Wmag, out);
}